// Round 5
// baseline (611.970 us; speedup 1.0000x reference)
//
#include <hip/hip_runtime.h>
#include <hip/hip_bf16.h>

typedef _Float16 half8 __attribute__((ext_vector_type(8)));
typedef _Float16 half4_t __attribute__((ext_vector_type(4)));
typedef _Float16 half2_t __attribute__((ext_vector_type(2)));
typedef float f32x4 __attribute__((ext_vector_type(4)));

#define B_SZ 64
#define T_SZ 512
#define E_SZ 768
#define H_SZ 256
#define V_SZ 3072

// workspace layout (bytes)
#define WS_X     0u          // _Float16 x[T][B][H]           16,777,216 B
#define WS_WT    16777216u   // _Float16 Wt[256][768] (Wxh^T)    393,216 B
#define WS_WF    17170432u   // _Float16 Wf[65536] Whh MFMA frags 131,072 B
#define WS_H     17301504u   // float    h[64][256]               65,536 B

// fast tanh: 1 - 2/(1+exp(2x)); exact at +/-inf, ~1e-6 rel err
static __device__ __forceinline__ float fast_tanh(float x) {
  float e = __builtin_amdgcn_exp2f(x * 2.8853900817779268f); // exp(2x)
  return 1.0f - 2.0f * __builtin_amdgcn_rcpf(1.0f + e);
}

// ---------------- k0: prep f16 layouts (small) ----------------
// Wt[h][e] = Wxh[e][h] (k1 B panels).
// Wf = Whh in 16x16x32 MFMA fragment order (r7-validated in the R0 session):
//   frag(nt,kt)[lane][j] = Whh[kt*32 + (lane>>4)*8 + j][nt*16 + (lane&15)]
//   flat = ((nt*8+kt)*64+lane)*8 + j
// In this round Wf is consumed as the A-operand (= Whh^T tiles for y^T = W^T h^T):
// A[row=n][k] = Whh[k][n] -> identical fragment data.
__global__ __launch_bounds__(256) void k0_convert(
    const float* __restrict__ Wxh,
    const float* __restrict__ Whh,
    _Float16* __restrict__ Wt,
    _Float16* __restrict__ Wf)
{
  int gid = blockIdx.x * 256 + threadIdx.x;           // 768 WGs = 196608
  if (gid < E_SZ * H_SZ) {
    int e = gid >> 8, h = gid & 255;
    Wt[h * E_SZ + e] = (_Float16)Wxh[gid];
  }
  if (gid < 65536) {
    int j = gid & 7, lane = (gid >> 3) & 63, kt = (gid >> 9) & 7, nt = gid >> 12;
    int quad = lane >> 4, n16 = lane & 15;
    int row = kt * 32 + quad * 8 + j, col = nt * 16 + n16;
    Wf[gid] = (_Float16)Whh[row * H_SZ + col];
  }
}

// ---------------- k1: x[t,b,:] = emb[idx[b,t],:] @ Wxh  (MFMA f16) ----------------
__global__ __launch_bounds__(256) void k1_xproj(
    const int* __restrict__ idx,
    const float* __restrict__ emb,
    const _Float16* __restrict__ Wt,
    _Float16* __restrict__ x)
{
  const int tid  = threadIdx.x;
  const int w    = tid >> 6;
  const int lane = tid & 63;
  const int m16  = lane & 15;
  const int quad = lane >> 4;
  const int r = blockIdx.x * 64 + w * 16 + m16;     // row in [T*B], r = t*64 + b
  const int t = r >> 6;
  const int b = r & 63;
  const int erow = idx[b * T_SZ + t];
  const float* Arow = emb + (size_t)erow * E_SZ + quad * 8;   // A[m][k=quad*8+j]

  __shared__ __align__(16) _Float16 bp[2][16 * 64 * 8]; // 2 x 16KB fragment panels
  int n_[4], kb_[4];
#pragma unroll
  for (int pp = 0; pp < 4; ++pp) {
    int f = tid + 256 * pp;
    n_[pp]  = ((f >> 6) << 4) | (f & 15);
    kb_[pp] = (f >> 4) & 3;
  }
  uint4 stg[4];
#pragma unroll
  for (int pp = 0; pp < 4; ++pp)
    stg[pp] = *(const uint4*)(Wt + (size_t)n_[pp] * E_SZ + kb_[pp] * 8);
  f32x4 af0 = *(const f32x4*)(Arow);
  f32x4 af1 = *(const f32x4*)(Arow + 4);

  f32x4 acc[16];
#pragma unroll
  for (int n = 0; n < 16; ++n) { f32x4 z = {0.f, 0.f, 0.f, 0.f}; acc[n] = z; }

  // stage panel 0
#pragma unroll
  for (int pp = 0; pp < 4; ++pp)
    *(uint4*)(bp[0] + (size_t)(tid + 256 * pp) * 8) = stg[pp];
  __syncthreads();

#pragma unroll 1
  for (int ki = 0; ki < 24; ++ki) {
    const _Float16* cur = bp[ki & 1];
    f32x4 af0n = af0, af1n = af1;
    if (ki < 23) {                            // prefetch next panel + next A
#pragma unroll
      for (int pp = 0; pp < 4; ++pp)
        stg[pp] = *(const uint4*)(Wt + (size_t)n_[pp] * E_SZ + (ki + 1) * 32 + kb_[pp] * 8);
      af0n = *(const f32x4*)(Arow + (ki + 1) * 32);
      af1n = *(const f32x4*)(Arow + (ki + 1) * 32 + 4);
    }
    half8 a;
#pragma unroll
    for (int e = 0; e < 4; ++e) { a[e] = (_Float16)af0[e]; a[4 + e] = (_Float16)af1[e]; }
#pragma unroll
    for (int nt = 0; nt < 16; ++nt) {
      half8 bb = *(const half8*)(cur + (size_t)(nt * 64 + lane) * 8);
      acc[nt] = __builtin_amdgcn_mfma_f32_16x16x32_f16(a, bb, acc[nt], 0, 0, 0);
    }
    if (ki < 23) {                            // write next buffer, one barrier
#pragma unroll
      for (int pp = 0; pp < 4; ++pp)
        *(uint4*)(bp[(ki + 1) & 1] + (size_t)(tid + 256 * pp) * 8) = stg[pp];
      __syncthreads();
    }
    af0 = af0n; af1 = af1n;
  }
  const int rbase = blockIdx.x * 64 + w * 16 + quad * 4;  // C/D: col=lane&15, row=quad*4+reg
#pragma unroll
  for (int nt = 0; nt < 16; ++nt) {
    const int col = nt * 16 + m16;
#pragma unroll
    for (int rg = 0; rg < 4; ++rg) {
      x[(size_t)(rbase + rg) * H_SZ + col] = (_Float16)acc[nt][rg];
    }
  }
}

// ---------------- k2: batched y^T MFMA recurrence ----------------
// R1-R4 post-mortem: every dot2 variant issued exactly 128 ds_read_b128 per
// CU-step (4x32 / 8x16 / 16x8) and every one ran 1330-1355 cyc/step:
// ~10.4 cyc per b128 on the CU's single LDS pipe = the wall. K-split only
// converts h-reads into partial read/writes (~same instr count + serial
// reduce phase). The MFMA matrix pipe is the only cheap broadcast engine
// (R0: 32 LDS instrs/step) -- its waste was the 16x-replicated A.
// Fix: M=16 real batches per block (4 blocks), computing y^T = Whh^T h^T:
//   A = Whh^T frags (static, AGPR-parked, same Wf data/layout R0 validated)
//   B = h frags: lane(m=lane&15, k=quad*8+j) <- row-major h[16][256] LDS,
//       ONE contiguous b128 per k-tile (XOR-swizzled kk ^= (m&7)<<3).
//   D: col=lane&15=m, row=quad*4+reg = n  -> writes straight back to the
//       same row-major layout as contiguous b64. No transpose anywhere.
// Per CU-step: 128 MFMA (~507 busy cyc, zero waste) over 32 b128 + 16 b64
// LDS instrs (~380 cyc, hidden), 1 barrier. 16 tanh/lane tail.
#define LDFRAG(C, KT, R0, R1, R2, R3) { \
  uint4 q = Wf4[(((size_t)(w * 4 + C) * 8 + KT) * 64) + lane]; \
  asm volatile("v_accvgpr_write_b32 a" #R0 ", %0" :: "v"(q.x) : "a" #R0); \
  asm volatile("v_accvgpr_write_b32 a" #R1 ", %0" :: "v"(q.y) : "a" #R1); \
  asm volatile("v_accvgpr_write_b32 a" #R2 ", %0" :: "v"(q.z) : "a" #R2); \
  asm volatile("v_accvgpr_write_b32 a" #R3 ", %0" :: "v"(q.w) : "a" #R3); }

// kt=0: fresh accumulators from pinned zero. srcA = AGPR W^T frag, srcB = h frag.
#define MFMA_K0(B0, Z) \
  asm volatile( \
    "v_mfma_f32_16x16x32_f16 %[t0], a[0:3],   %[b], %[z]\n\t" \
    "v_mfma_f32_16x16x32_f16 %[t1], a[32:35], %[b], %[z]\n\t" \
    "v_mfma_f32_16x16x32_f16 %[t2], a[64:67], %[b], %[z]\n\t" \
    "v_mfma_f32_16x16x32_f16 %[t3], a[96:99], %[b], %[z]" \
    : [t0] "=&v"(acc0), [t1] "=&v"(acc1), [t2] "=&v"(acc2), [t3] "=&v"(acc3) \
    : [b] "v"(B0), [z] "v"(Z));

#define MFMA_KT(B0, A0, A1, A2, A3) \
  asm volatile( \
    "v_mfma_f32_16x16x32_f16 %[t0], a[" #A0 "], %[b], %[t0]\n\t" \
    "v_mfma_f32_16x16x32_f16 %[t1], a[" #A1 "], %[b], %[t1]\n\t" \
    "v_mfma_f32_16x16x32_f16 %[t2], a[" #A2 "], %[b], %[t2]\n\t" \
    "v_mfma_f32_16x16x32_f16 %[t3], a[" #A3 "], %[b], %[t3]" \
    : [t0] "+v"(acc0), [t1] "+v"(acc1), [t2] "+v"(acc2), [t3] "+v"(acc3) \
    : [b] "v"(B0));

#define MFMA_K7(B0, A0, A1, A2, A3) \
  asm volatile( \
    "v_mfma_f32_16x16x32_f16 %[t0], a[" #A0 "], %[b], %[t0]\n\t" \
    "v_mfma_f32_16x16x32_f16 %[t1], a[" #A1 "], %[b], %[t1]\n\t" \
    "v_mfma_f32_16x16x32_f16 %[t2], a[" #A2 "], %[b], %[t2]\n\t" \
    "v_mfma_f32_16x16x32_f16 %[t3], a[" #A3 "], %[b], %[t3]\n\t" \
    "s_nop 7\n\t" \
    "s_nop 7" \
    : [t0] "+v"(acc0), [t1] "+v"(acc1), [t2] "+v"(acc2), [t3] "+v"(acc3) \
    : [b] "v"(B0));

__global__ __launch_bounds__(256, 1) void k2_rnn(
    const _Float16* __restrict__ Wf,
    const _Float16* __restrict__ x,
    const float* __restrict__ Bh,
    float* __restrict__ hout,
    float* __restrict__ hidout)
{
  const int blk  = blockIdx.x;          // 4 blocks x 16 batches
  const int tid  = threadIdx.x;
  const int w    = tid >> 6;            // wave owns nt = 4w..4w+3
  const int lane = tid & 63;
  const int m    = lane & 15;           // batch within block (fixed per lane)
  const int quad = lane >> 4;
  const int swz  = (m & 7) << 3;        // f16-index XOR swizzle (bank spread)
  __shared__ __align__(16) _Float16 hs[2][16 * H_SZ];  // h[m][k], double-buffered
  const uint4* Wf4 = (const uint4*)Wf;

  LDFRAG(0,0,  0,  1,  2,  3)  LDFRAG(0,1,  4,  5,  6,  7)
  LDFRAG(0,2,  8,  9, 10, 11)  LDFRAG(0,3, 12, 13, 14, 15)
  LDFRAG(0,4, 16, 17, 18, 19)  LDFRAG(0,5, 20, 21, 22, 23)
  LDFRAG(0,6, 24, 25, 26, 27)  LDFRAG(0,7, 28, 29, 30, 31)
  LDFRAG(1,0, 32, 33, 34, 35)  LDFRAG(1,1, 36, 37, 38, 39)
  LDFRAG(1,2, 40, 41, 42, 43)  LDFRAG(1,3, 44, 45, 46, 47)
  LDFRAG(1,4, 48, 49, 50, 51)  LDFRAG(1,5, 52, 53, 54, 55)
  LDFRAG(1,6, 56, 57, 58, 59)  LDFRAG(1,7, 60, 61, 62, 63)
  LDFRAG(2,0, 64, 65, 66, 67)  LDFRAG(2,1, 68, 69, 70, 71)
  LDFRAG(2,2, 72, 73, 74, 75)  LDFRAG(2,3, 76, 77, 78, 79)
  LDFRAG(2,4, 80, 81, 82, 83)  LDFRAG(2,5, 84, 85, 86, 87)
  LDFRAG(2,6, 88, 89, 90, 91)  LDFRAG(2,7, 92, 93, 94, 95)
  LDFRAG(3,0, 96, 97, 98, 99)  LDFRAG(3,1,100,101,102,103)
  LDFRAG(3,2,104,105,106,107)  LDFRAG(3,3,108,109,110,111)
  LDFRAG(3,4,112,113,114,115)  LDFRAG(3,5,116,117,118,119)
  LDFRAG(3,6,120,121,122,123)  LDFRAG(3,7,124,125,126,127)

  // Bh for this lane's 16 hidden outputs: n = (4w+c)*16 + quad*4 + r
  float bhv[16];
#pragma unroll
  for (int c = 0; c < 4; ++c)
#pragma unroll
    for (int r = 0; r < 4; ++r)
      bhv[c * 4 + r] = Bh[(w * 4 + c) * 16 + quad * 4 + r];

  // x base for this lane's batch row: x[t][blk*16+m][n]
  const _Float16* xb = x + (size_t)(blk * 16 + m) * H_SZ;
  uint2 xq0, xq1, xq2, xq3;   // current step's 4 b64 x slices (per nt)
  {
    const _Float16* xp0 = xb;    // t = 0
    xq0 = *(const uint2*)(xp0 + (w * 4 + 0) * 16 + quad * 4);
    xq1 = *(const uint2*)(xp0 + (w * 4 + 1) * 16 + quad * 4);
    xq2 = *(const uint2*)(xp0 + (w * 4 + 2) * 16 + quad * 4);
    xq3 = *(const uint2*)(xp0 + (w * 4 + 3) * 16 + quad * 4);
  }

  f32x4 zero4 = {0.f, 0.f, 0.f, 0.f};
  asm volatile("" : "+v"(zero4));        // pin: no remat-mov adjacent to MFMA srcC
  // t=0 reads buffer 1 = zeros
#pragma unroll
  for (int i = 0; i < 16; ++i) hs[1][tid + 256 * i] = (_Float16)0.f;
  __syncthreads();

#pragma unroll 1
  for (int t = 0; t < T_SZ; ++t) {
    // prefetch next step's x (consumed at the end of the NEXT iteration)
    const int tn = (t < T_SZ - 1) ? (t + 1) : t;
    const _Float16* xpn = xb + (size_t)tn * (B_SZ * H_SZ);
    uint2 xn0 = *(const uint2*)(xpn + (w * 4 + 0) * 16 + quad * 4);
    uint2 xn1 = *(const uint2*)(xpn + (w * 4 + 1) * 16 + quad * 4);
    uint2 xn2 = *(const uint2*)(xpn + (w * 4 + 2) * 16 + quad * 4);
    uint2 xn3 = *(const uint2*)(xpn + (w * 4 + 3) * 16 + quad * 4);

    const _Float16* hr = hs[(t + 1) & 1];
    _Float16*       hw = hs[t & 1];

    // B-frags: lane (m, quad) reads h[m][kt*32 + quad*8 .. +7], swizzled, b128
    const _Float16* hrm = hr + m * H_SZ;
    uint4 vb0 = *(const uint4*)(hrm + (( 0 * 32 + quad * 8) ^ swz));
    uint4 vb1 = *(const uint4*)(hrm + (( 1 * 32 + quad * 8) ^ swz));
    uint4 vb2 = *(const uint4*)(hrm + (( 2 * 32 + quad * 8) ^ swz));
    uint4 vb3 = *(const uint4*)(hrm + (( 3 * 32 + quad * 8) ^ swz));
    uint4 vb4 = *(const uint4*)(hrm + (( 4 * 32 + quad * 8) ^ swz));
    uint4 vb5 = *(const uint4*)(hrm + (( 5 * 32 + quad * 8) ^ swz));
    uint4 vb6 = *(const uint4*)(hrm + (( 6 * 32 + quad * 8) ^ swz));
    uint4 vb7 = *(const uint4*)(hrm + (( 7 * 32 + quad * 8) ^ swz));

    f32x4 acc0, acc1, acc2, acc3;
    MFMA_K0(__builtin_bit_cast(half8, vb0), zero4)
    MFMA_KT(__builtin_bit_cast(half8, vb1),   4:7,  36:39,  68:71, 100:103)
    MFMA_KT(__builtin_bit_cast(half8, vb2),  8:11,  40:43,  72:75, 104:107)
    MFMA_KT(__builtin_bit_cast(half8, vb3), 12:15,  44:47,  76:79, 108:111)
    MFMA_KT(__builtin_bit_cast(half8, vb4), 16:19,  48:51,  80:83, 112:115)
    MFMA_KT(__builtin_bit_cast(half8, vb5), 20:23,  52:55,  84:87, 116:119)
    MFMA_KT(__builtin_bit_cast(half8, vb6), 24:27,  56:59,  88:91, 120:123)
    MFMA_K7(__builtin_bit_cast(half8, vb7), 28:31,  60:63,  92:95, 124:127)

    // epilogue: h_new[m][n] = tanh(y^T[n][m] + x[t][m][n] + Bh[n]); b64 writes
#define EPI(C, ACC, XQ) { \
    half4_t xf = __builtin_bit_cast(half4_t, XQ); \
    float y0 = fast_tanh(ACC[0] + (float)xf[0] + bhv[C * 4 + 0]); \
    float y1 = fast_tanh(ACC[1] + (float)xf[1] + bhv[C * 4 + 1]); \
    float y2 = fast_tanh(ACC[2] + (float)xf[2] + bhv[C * 4 + 2]); \
    float y3 = fast_tanh(ACC[3] + (float)xf[3] + bhv[C * 4 + 3]); \
    half2_t plo; plo[0] = (_Float16)y0; plo[1] = (_Float16)y1; \
    half2_t phi; phi[0] = (_Float16)y2; phi[1] = (_Float16)y3; \
    uint2 pk; pk.x = __builtin_bit_cast(unsigned int, plo); \
    pk.y = __builtin_bit_cast(unsigned int, phi); \
    *(uint2*)(hw + m * H_SZ + ((((w * 4 + C) * 16 + quad * 4)) ^ swz)) = pk; }
    EPI(0, acc0, xq0)
    EPI(1, acc1, xq1)
    EPI(2, acc2, xq2)
    EPI(3, acc3, xq3)
#undef EPI
    __syncthreads();
    xq0 = xn0; xq1 = xn1; xq2 = xn2; xq3 = xn3;
  }

  // final h lives in hs[511 & 1] = hs[1]
#pragma unroll
  for (int i = 0; i < 16; ++i) {
    int idx = tid + 256 * i;            // [0, 4096)
    int mm = idx >> 8, nn = idx & 255;
    float v = (float)hs[1][mm * H_SZ + (nn ^ ((mm & 7) << 3))];
    hout[(size_t)(blk * 16 + mm) * H_SZ + nn]   = v;
    hidout[(size_t)(blk * 16 + mm) * H_SZ + nn] = v;
  }
}

// ---------------- k3: out = hidden @ Wy + By  (all f32) ----------------
__global__ __launch_bounds__(256) void k3_out(
    const float* __restrict__ h,
    const float* __restrict__ Wy,
    const float* __restrict__ By,
    float* __restrict__ out)
{
  __shared__ float hs[H_SZ];
  const int c = blockIdx.x;   // vocab chunk
  const int b = blockIdx.y;   // batch
  const int v = c * 256 + threadIdx.x;
  hs[threadIdx.x] = h[b * H_SZ + threadIdx.x];
  __syncthreads();
  float acc = By[v];
#pragma unroll 8
  for (int jj = 0; jj < H_SZ; ++jj) {
    acc += hs[jj] * Wy[(size_t)jj * V_SZ + v];
  }
  out[(size_t)b * V_SZ + v] = acc;
}

extern "C" void kernel_launch(void* const* d_in, const int* in_sizes, int n_in,
                              void* d_out, int out_size, void* d_ws, size_t ws_size,
                              hipStream_t stream)
{
  const int*   idx = (const int*)d_in[0];
  const float* emb = (const float*)d_in[1];
  const float* Wxh = (const float*)d_in[2];
  const float* Whh = (const float*)d_in[3];
  const float* Wy  = (const float*)d_in[4];
  const float* By  = (const float*)d_in[5];
  const float* Bh  = (const float*)d_in[6];

  char* ws = (char*)d_ws;
  _Float16* x    = (_Float16*)(ws + WS_X);
  _Float16* Wt   = (_Float16*)(ws + WS_WT);
  _Float16* Wf   = (_Float16*)(ws + WS_WF);
  float*    hbuf = (float*)(ws + WS_H);

  float* out    = (float*)d_out;
  float* hidout = out + (size_t)B_SZ * V_SZ;

  k0_convert<<<768, 256, 0, stream>>>(Wxh, Whh, Wt, Wf);
  k1_xproj  <<<512, 256, 0, stream>>>(idx, emb, Wt, x);
  k2_rnn    <<<4, 256, 0, stream>>>(Wf, x, Bh, hbuf, hidout);
  k3_out    <<<dim3(12, 64), 256, 0, stream>>>(hbuf, Wy, By, out);
}

// Round 6
// 377.437 us; speedup vs baseline: 1.6214x; 1.6214x over previous
//
#include <hip/hip_runtime.h>
#include <hip/hip_bf16.h>

typedef _Float16 half8 __attribute__((ext_vector_type(8)));
typedef float f32x4 __attribute__((ext_vector_type(4)));

#define B_SZ 64
#define T_SZ 512
#define E_SZ 768
#define H_SZ 256
#define V_SZ 3072

// workspace layout (bytes)
#define WS_X     0u          // _Float16 x[T][B][H]           16,777,216 B
#define WS_WT    16777216u   // _Float16 Wtf[24][1024][8] (Wxh panels, frag order) 393,216 B
#define WS_WF    17170432u   // _Float16 Wf[65536] Whh MFMA-B    131,072 B
#define WS_H     17301504u   // float    h[64][256]               65,536 B

// fast tanh: 1 - 2/(1+exp(2x)); exact at +/-inf, ~1e-6 rel err
static __device__ __forceinline__ float fast_tanh(float x) {
  float e = __builtin_amdgcn_exp2f(x * 2.8853900817779268f); // exp(2x)
  return 1.0f - 2.0f * __builtin_amdgcn_rcpf(1.0f + e);
}

// ---------------- k0: prep f16 weight layouts (small) ----------------
// Wtf = Wxh in k1's staging order: Wtf[ki][f][j] with f = tid+256*pp,
//   n_ = ((f>>6)<<4)|(f&15), kb = (f>>4)&3, e = ki*32+kb*8+j:
//   Wtf[flat] = Wxh[e][n_]  -> k1 staging becomes contiguous coalesced uint4.
// Wf = Whh in 16x16x32 MFMA-B fragment order (r7-validated):
//   frag(nt,kt)[lane][j] = Whh[kt*32 + (lane>>4)*8 + j][nt*16 + (lane&15)]
//   flat = ((nt*8+kt)*64+lane)*8 + j
__global__ __launch_bounds__(256) void k0_convert(
    const float* __restrict__ Wxh,
    const float* __restrict__ Whh,
    _Float16* __restrict__ Wtf,
    _Float16* __restrict__ Wf)
{
  int gid = blockIdx.x * 256 + threadIdx.x;           // 768 WGs = 196608
  if (gid < 24 * 8192) {                              // = E_SZ*H_SZ elements
    int j = gid & 7, f = (gid >> 3) & 1023, ki = gid >> 13;
    int kb = (f >> 4) & 3;
    int n_ = ((f >> 6) << 4) | (f & 15);
    int e  = ki * 32 + kb * 8 + j;
    Wtf[gid] = (_Float16)Wxh[e * H_SZ + n_];
  }
  if (gid < 65536) {
    int j = gid & 7, lane = (gid >> 3) & 63, kt = (gid >> 9) & 7, nt = gid >> 12;
    int quad = lane >> 4, n16 = lane & 15;
    int row = kt * 32 + quad * 8 + j, col = nt * 16 + n16;
    Wf[gid] = (_Float16)Whh[row * H_SZ + col];
  }
}

// ---------------- k1: x[t,b,:] = emb[idx[b,t],:] @ Wxh  (MFMA f16) ----------------
// Double-buffered B panel, ONE barrier per ki. Staging now reads Wtf in
// fragment order: per-wave fully contiguous 1 KB bursts (was 64 x 16B
// requests strided 1536 B -> ~4x L2 transaction waste).
__global__ __launch_bounds__(256) void k1_xproj(
    const int* __restrict__ idx,
    const float* __restrict__ emb,
    const _Float16* __restrict__ Wtf,
    _Float16* __restrict__ x)
{
  const int tid  = threadIdx.x;
  const int w    = tid >> 6;
  const int lane = tid & 63;
  const int m16  = lane & 15;
  const int quad = lane >> 4;
  const int r = blockIdx.x * 64 + w * 16 + m16;     // row in [T*B], r = t*64 + b
  const int t = r >> 6;
  const int b = r & 63;
  const int erow = idx[b * T_SZ + t];
  const float* Arow = emb + (size_t)erow * E_SZ + quad * 8;   // A[m][k=quad*8+j]

  __shared__ __align__(16) _Float16 bp[2][16 * 64 * 8]; // 2 x 16KB fragment panels
  uint4 stg[4];
#pragma unroll
  for (int pp = 0; pp < 4; ++pp)
    stg[pp] = *(const uint4*)(Wtf + (size_t)(tid + 256 * pp) * 8);  // ki = 0
  f32x4 af0 = *(const f32x4*)(Arow);
  f32x4 af1 = *(const f32x4*)(Arow + 4);

  f32x4 acc[16];
#pragma unroll
  for (int n = 0; n < 16; ++n) { f32x4 z = {0.f, 0.f, 0.f, 0.f}; acc[n] = z; }

  // stage panel 0
#pragma unroll
  for (int pp = 0; pp < 4; ++pp)
    *(uint4*)(bp[0] + (size_t)(tid + 256 * pp) * 8) = stg[pp];
  __syncthreads();

#pragma unroll 1
  for (int ki = 0; ki < 24; ++ki) {
    const _Float16* cur = bp[ki & 1];
    f32x4 af0n = af0, af1n = af1;
    if (ki < 23) {                            // prefetch next panel + next A
#pragma unroll
      for (int pp = 0; pp < 4; ++pp)
        stg[pp] = *(const uint4*)(Wtf + (size_t)(ki + 1) * 8192
                                      + (size_t)(tid + 256 * pp) * 8);
      af0n = *(const f32x4*)(Arow + (ki + 1) * 32);
      af1n = *(const f32x4*)(Arow + (ki + 1) * 32 + 4);
    }
    half8 a;
#pragma unroll
    for (int e = 0; e < 4; ++e) { a[e] = (_Float16)af0[e]; a[4 + e] = (_Float16)af1[e]; }
#pragma unroll
    for (int nt = 0; nt < 16; ++nt) {
      half8 bb = *(const half8*)(cur + (size_t)(nt * 64 + lane) * 8);
      acc[nt] = __builtin_amdgcn_mfma_f32_16x16x32_f16(a, bb, acc[nt], 0, 0, 0);
    }
    if (ki < 23) {                            // write next buffer, one barrier
#pragma unroll
      for (int pp = 0; pp < 4; ++pp)
        *(uint4*)(bp[(ki + 1) & 1] + (size_t)(tid + 256 * pp) * 8) = stg[pp];
      __syncthreads();
    }
    af0 = af0n; af1 = af1n;
  }
  const int rbase = blockIdx.x * 64 + w * 16 + quad * 4;  // C/D: col=lane&15, row=quad*4+reg
#pragma unroll
  for (int nt = 0; nt < 16; ++nt) {
    const int col = nt * 16 + m16;
#pragma unroll
    for (int rg = 0; rg < 4; ++rg) {
      x[(size_t)(rbase + rg) * H_SZ + col] = (_Float16)acc[nt][rg];
    }
  }
}

// ---------------- k2: r7's proven MFMA recurrence, per-K-tile asm split ----
// VERBATIM revert to the session-best kernel (230.3 us measured, R0).
// Five structural alternatives (dot2 x3, VGPR-pin, batched-y^T) all measured
// 287-447 us; accounting shows per-CU step cost (128 MFMA + ~32 wave-LDS ops)
// is invariant to batches-per-block, so this 64-CU form is the best-measured
// point of a ~170-190 us-floor family. Do not restructure further.
#define LDFRAG(C, KT, R0, R1, R2, R3) { \
  uint4 q = Wf4[(((size_t)(w * 4 + C) * 8 + KT) * 64) + lane]; \
  asm volatile("v_accvgpr_write_b32 a" #R0 ", %0" :: "v"(q.x) : "a" #R0); \
  asm volatile("v_accvgpr_write_b32 a" #R1 ", %0" :: "v"(q.y) : "a" #R1); \
  asm volatile("v_accvgpr_write_b32 a" #R2 ", %0" :: "v"(q.z) : "a" #R2); \
  asm volatile("v_accvgpr_write_b32 a" #R3 ", %0" :: "v"(q.w) : "a" #R3); }

// kt=0: fresh accumulators from pinned zero
#define MFMA_K0(A0, Z) \
  asm volatile( \
    "v_mfma_f32_16x16x32_f16 %[t0], %[a], a[0:3],   %[z]\n\t" \
    "v_mfma_f32_16x16x32_f16 %[t1], %[a], a[32:35], %[z]\n\t" \
    "v_mfma_f32_16x16x32_f16 %[t2], %[a], a[64:67], %[z]\n\t" \
    "v_mfma_f32_16x16x32_f16 %[t3], %[a], a[96:99], %[z]" \
    : [t0] "=&v"(acc0), [t1] "=&v"(acc1), [t2] "=&v"(acc2), [t3] "=&v"(acc3) \
    : [a] "v"(A0), [z] "v"(Z));

#define MFMA_KT(A0, B0, B1, B2, B3) \
  asm volatile( \
    "v_mfma_f32_16x16x32_f16 %[t0], %[a], a[" #B0 "], %[t0]\n\t" \
    "v_mfma_f32_16x16x32_f16 %[t1], %[a], a[" #B1 "], %[t1]\n\t" \
    "v_mfma_f32_16x16x32_f16 %[t2], %[a], a[" #B2 "], %[t2]\n\t" \
    "v_mfma_f32_16x16x32_f16 %[t3], %[a], a[" #B3 "], %[t3]" \
    : [t0] "+v"(acc0), [t1] "+v"(acc1), [t2] "+v"(acc2), [t3] "+v"(acc3) \
    : [a] "v"(A0));

#define MFMA_K7(A0, B0, B1, B2, B3) \
  asm volatile( \
    "v_mfma_f32_16x16x32_f16 %[t0], %[a], a[" #B0 "], %[t0]\n\t" \
    "v_mfma_f32_16x16x32_f16 %[t1], %[a], a[" #B1 "], %[t1]\n\t" \
    "v_mfma_f32_16x16x32_f16 %[t2], %[a], a[" #B2 "], %[t2]\n\t" \
    "v_mfma_f32_16x16x32_f16 %[t3], %[a], a[" #B3 "], %[t3]\n\t" \
    "s_nop 7\n\t" \
    "s_nop 7" \
    : [t0] "+v"(acc0), [t1] "+v"(acc1), [t2] "+v"(acc2), [t3] "+v"(acc3) \
    : [a] "v"(A0));

__global__ __launch_bounds__(256) void k2_rnn(
    const _Float16* __restrict__ Wf,
    const _Float16* __restrict__ x,
    const float* __restrict__ Bh,
    float* __restrict__ hout,
    float* __restrict__ hidout)
{
  const int b    = blockIdx.x;
  const int tid  = threadIdx.x;
  const int w    = tid >> 6;
  const int lane = tid & 63;
  const int quad = lane >> 4;
  __shared__ __align__(16) _Float16 hb[2][H_SZ];   // h as f16, double-buffered
  const uint4* Wf4 = (const uint4*)Wf;

  LDFRAG(0,0,  0,  1,  2,  3)  LDFRAG(0,1,  4,  5,  6,  7)
  LDFRAG(0,2,  8,  9, 10, 11)  LDFRAG(0,3, 12, 13, 14, 15)
  LDFRAG(0,4, 16, 17, 18, 19)  LDFRAG(0,5, 20, 21, 22, 23)
  LDFRAG(0,6, 24, 25, 26, 27)  LDFRAG(0,7, 28, 29, 30, 31)
  LDFRAG(1,0, 32, 33, 34, 35)  LDFRAG(1,1, 36, 37, 38, 39)
  LDFRAG(1,2, 40, 41, 42, 43)  LDFRAG(1,3, 44, 45, 46, 47)
  LDFRAG(1,4, 48, 49, 50, 51)  LDFRAG(1,5, 52, 53, 54, 55)
  LDFRAG(1,6, 56, 57, 58, 59)  LDFRAG(1,7, 60, 61, 62, 63)
  LDFRAG(2,0, 64, 65, 66, 67)  LDFRAG(2,1, 68, 69, 70, 71)
  LDFRAG(2,2, 72, 73, 74, 75)  LDFRAG(2,3, 76, 77, 78, 79)
  LDFRAG(2,4, 80, 81, 82, 83)  LDFRAG(2,5, 84, 85, 86, 87)
  LDFRAG(2,6, 88, 89, 90, 91)  LDFRAG(2,7, 92, 93, 94, 95)
  LDFRAG(3,0, 96, 97, 98, 99)  LDFRAG(3,1,100,101,102,103)
  LDFRAG(3,2,104,105,106,107)  LDFRAG(3,3,108,109,110,111)
  LDFRAG(3,4,112,113,114,115)  LDFRAG(3,5,116,117,118,119)
  LDFRAG(3,6,120,121,122,123)  LDFRAG(3,7,124,125,126,127)

  const float bhj = Bh[tid];
  const _Float16* xp = x + b * H_SZ + tid;
  _Float16 xq = xp[0];
  f32x4 zero4 = {0.f, 0.f, 0.f, 0.f};
  asm volatile("" : "+v"(zero4));        // pin: no remat-mov adjacent to MFMA srcC
  hb[1][tid] = (_Float16)0.f;            // t=0 reads buffer 1 = zeros
  float hval = 0.f;
  __syncthreads();

#pragma unroll 1
  for (int t = 0; t < T_SZ; ++t) {
    const int tn = (t < T_SZ - 1) ? (t + 1) : t;
    _Float16 xn = xp[(size_t)tn * (B_SZ * H_SZ)];   // prefetch next x
    const _Float16* hr = hb[(t + 1) & 1];
    // A fragments: h[kt*32+quad*8 .. +7], same for all 16 rows (quad-broadcast)
    half8 va0 = *(const half8*)(hr +   0 + quad * 8);
    half8 va1 = *(const half8*)(hr +  32 + quad * 8);
    half8 va2 = *(const half8*)(hr +  64 + quad * 8);
    half8 va3 = *(const half8*)(hr +  96 + quad * 8);
    half8 va4 = *(const half8*)(hr + 128 + quad * 8);
    half8 va5 = *(const half8*)(hr + 160 + quad * 8);
    half8 va6 = *(const half8*)(hr + 192 + quad * 8);
    half8 va7 = *(const half8*)(hr + 224 + quad * 8);
    f32x4 acc0, acc1, acc2, acc3;
    MFMA_K0(va0, zero4)
    MFMA_KT(va1,   4:7,  36:39,  68:71, 100:103)
    MFMA_KT(va2,  8:11,  40:43,  72:75, 104:107)
    MFMA_KT(va3, 12:15,  44:47,  76:79, 108:111)
    MFMA_KT(va4, 16:19,  48:51,  80:83, 112:115)
    MFMA_KT(va5, 20:23,  52:55,  84:87, 116:119)
    MFMA_KT(va6, 24:27,  56:59,  88:91, 120:123)
    MFMA_K7(va7, 28:31,  60:63,  92:95, 124:127)
    // D rows identical (A rows replicated); lane (quad q, n16) takes tile q:
    float v0 = acc0[0], v1 = acc1[0], v2 = acc2[0], v3 = acc3[0];
    float ylo = (quad & 1) ? v1 : v0;
    float yhi = (quad & 1) ? v3 : v2;
    float y   = (quad & 2) ? yhi : ylo;     // y = (h @ Whh)[tid]
    hval = fast_tanh(y + (float)xq + bhj);
    hb[t & 1][tid] = (_Float16)hval;
    __syncthreads();
    xq = xn;
  }
  hout[b * H_SZ + tid] = hval;
  hidout[b * H_SZ + tid] = hval;
}

// ---------------- k3: out = hidden @ Wy + By  (all f32) ----------------
__global__ __launch_bounds__(256) void k3_out(
    const float* __restrict__ h,
    const float* __restrict__ Wy,
    const float* __restrict__ By,
    float* __restrict__ out)
{
  __shared__ float hs[H_SZ];
  const int c = blockIdx.x;   // vocab chunk
  const int b = blockIdx.y;   // batch
  const int v = c * 256 + threadIdx.x;
  hs[threadIdx.x] = h[b * H_SZ + threadIdx.x];
  __syncthreads();
  float acc = By[v];
#pragma unroll 8
  for (int jj = 0; jj < H_SZ; ++jj) {
    acc += hs[jj] * Wy[(size_t)jj * V_SZ + v];
  }
  out[(size_t)b * V_SZ + v] = acc;
}

extern "C" void kernel_launch(void* const* d_in, const int* in_sizes, int n_in,
                              void* d_out, int out_size, void* d_ws, size_t ws_size,
                              hipStream_t stream)
{
  const int*   idx = (const int*)d_in[0];
  const float* emb = (const float*)d_in[1];
  const float* Wxh = (const float*)d_in[2];
  const float* Whh = (const float*)d_in[3];
  const float* Wy  = (const float*)d_in[4];
  const float* By  = (const float*)d_in[5];
  const float* Bh  = (const float*)d_in[6];

  char* ws = (char*)d_ws;
  _Float16* x    = (_Float16*)(ws + WS_X);
  _Float16* Wtf  = (_Float16*)(ws + WS_WT);
  _Float16* Wf   = (_Float16*)(ws + WS_WF);
  float*    hbuf = (float*)(ws + WS_H);

  float* out    = (float*)d_out;
  float* hidout = out + (size_t)B_SZ * V_SZ;

  k0_convert<<<768, 256, 0, stream>>>(Wxh, Whh, Wtf, Wf);
  k1_xproj  <<<512, 256, 0, stream>>>(idx, emb, Wtf, x);
  k2_rnn    <<<64, 256, 0, stream>>>(Wf, x, Bh, hbuf, hidout);
  k3_out    <<<dim3(12, 64), 256, 0, stream>>>(hbuf, Wy, By, out);
}

// Round 7
// 369.956 us; speedup vs baseline: 1.6542x; 1.0202x over previous
//
#include <hip/hip_runtime.h>
#include <hip/hip_bf16.h>

typedef _Float16 half8 __attribute__((ext_vector_type(8)));
typedef float f32x4 __attribute__((ext_vector_type(4)));

#define B_SZ 64
#define T_SZ 512
#define E_SZ 768
#define H_SZ 256
#define V_SZ 3072

// workspace layout (bytes)
#define WS_P     0u          // _Float16 P[3072][256] = emb @ Wxh   1,572,864 B
#define WS_WT    16777216u   // _Float16 Wtf[24][1024][8] (Wxh panels, frag order) 393,216 B
#define WS_WF    17170432u   // _Float16 Wf[65536] Whh MFMA-B    131,072 B
#define WS_H     17301504u   // float    h[64][256]               65,536 B

// fast tanh: 1 - 2/(1+exp(2x)); exact at +/-inf, ~1e-6 rel err
static __device__ __forceinline__ float fast_tanh(float x) {
  float e = __builtin_amdgcn_exp2f(x * 2.8853900817779268f); // exp(2x)
  return 1.0f - 2.0f * __builtin_amdgcn_rcpf(1.0f + e);
}

// ---------------- k0: prep f16 weight layouts (small) ----------------
// Wtf = Wxh in k1's staging order: Wtf[ki][f][j] with f = tid+256*pp,
//   n_ = ((f>>6)<<4)|(f&15), kb = (f>>4)&3, e = ki*32+kb*8+j:
//   Wtf[flat] = Wxh[e][n_]  -> k1 staging is contiguous coalesced uint4.
// Wf = Whh in 16x16x32 MFMA-B fragment order (r7-validated):
//   frag(nt,kt)[lane][j] = Whh[kt*32 + (lane>>4)*8 + j][nt*16 + (lane&15)]
//   flat = ((nt*8+kt)*64+lane)*8 + j
__global__ __launch_bounds__(256) void k0_convert(
    const float* __restrict__ Wxh,
    const float* __restrict__ Whh,
    _Float16* __restrict__ Wtf,
    _Float16* __restrict__ Wf)
{
  int gid = blockIdx.x * 256 + threadIdx.x;           // 768 WGs = 196608
  if (gid < 24 * 8192) {                              // = E_SZ*H_SZ elements
    int j = gid & 7, f = (gid >> 3) & 1023, ki = gid >> 13;
    int kb = (f >> 4) & 3;
    int n_ = ((f >> 6) << 4) | (f & 15);
    int e  = ki * 32 + kb * 8 + j;
    Wtf[gid] = (_Float16)Wxh[e * H_SZ + n_];
  }
  if (gid < 65536) {
    int j = gid & 7, lane = (gid >> 3) & 63, kt = (gid >> 9) & 7, nt = gid >> 12;
    int quad = lane >> 4, n16 = lane & 15;
    int row = kt * 32 + quad * 8 + j, col = nt * 16 + n16;
    Wf[gid] = (_Float16)Whh[row * H_SZ + col];
  }
}

// ---------------- k1: P[v,:] = emb[v,:] @ Wxh  (MFMA f16, vocab table) ---------
// KEY CHANGE (R6->R7): idx only selects among 3072 distinct emb rows, so
// project the TABLE once (3072 rows) instead of all 32768 (t,b) duplicates:
// 10.7x less MFMA work, and the 16.7 MB x tensor is never materialized --
// k2 gathers directly from P (1.5 MB, L2-resident). Bit-identical numerics:
// same MFMA on the same rows, computed once per unique row.
// Grid: 48 blocks x 64 rows. Inner loop identical to the proven R6 k1.
__global__ __launch_bounds__(256) void k1_xproj(
    const float* __restrict__ emb,
    const _Float16* __restrict__ Wtf,
    _Float16* __restrict__ P)
{
  const int tid  = threadIdx.x;
  const int w    = tid >> 6;
  const int lane = tid & 63;
  const int m16  = lane & 15;
  const int quad = lane >> 4;
  const int r = blockIdx.x * 64 + w * 16 + m16;     // vocab row, 0..3071
  const float* Arow = emb + (size_t)r * E_SZ + quad * 8;   // A[m][k=quad*8+j]

  __shared__ __align__(16) _Float16 bp[2][16 * 64 * 8]; // 2 x 16KB fragment panels
  uint4 stg[4];
#pragma unroll
  for (int pp = 0; pp < 4; ++pp)
    stg[pp] = *(const uint4*)(Wtf + (size_t)(tid + 256 * pp) * 8);  // ki = 0
  f32x4 af0 = *(const f32x4*)(Arow);
  f32x4 af1 = *(const f32x4*)(Arow + 4);

  f32x4 acc[16];
#pragma unroll
  for (int n = 0; n < 16; ++n) { f32x4 z = {0.f, 0.f, 0.f, 0.f}; acc[n] = z; }

  // stage panel 0
#pragma unroll
  for (int pp = 0; pp < 4; ++pp)
    *(uint4*)(bp[0] + (size_t)(tid + 256 * pp) * 8) = stg[pp];
  __syncthreads();

#pragma unroll 1
  for (int ki = 0; ki < 24; ++ki) {
    const _Float16* cur = bp[ki & 1];
    f32x4 af0n = af0, af1n = af1;
    if (ki < 23) {                            // prefetch next panel + next A
#pragma unroll
      for (int pp = 0; pp < 4; ++pp)
        stg[pp] = *(const uint4*)(Wtf + (size_t)(ki + 1) * 8192
                                      + (size_t)(tid + 256 * pp) * 8);
      af0n = *(const f32x4*)(Arow + (ki + 1) * 32);
      af1n = *(const f32x4*)(Arow + (ki + 1) * 32 + 4);
    }
    half8 a;
#pragma unroll
    for (int e = 0; e < 4; ++e) { a[e] = (_Float16)af0[e]; a[4 + e] = (_Float16)af1[e]; }
#pragma unroll
    for (int nt = 0; nt < 16; ++nt) {
      half8 bb = *(const half8*)(cur + (size_t)(nt * 64 + lane) * 8);
      acc[nt] = __builtin_amdgcn_mfma_f32_16x16x32_f16(a, bb, acc[nt], 0, 0, 0);
    }
    if (ki < 23) {                            // write next buffer, one barrier
#pragma unroll
      for (int pp = 0; pp < 4; ++pp)
        *(uint4*)(bp[(ki + 1) & 1] + (size_t)(tid + 256 * pp) * 8) = stg[pp];
      __syncthreads();
    }
    af0 = af0n; af1 = af1n;
  }
  const int rbase = blockIdx.x * 64 + w * 16 + quad * 4;  // C/D: col=lane&15, row=quad*4+reg
#pragma unroll
  for (int nt = 0; nt < 16; ++nt) {
    const int col = nt * 16 + m16;
#pragma unroll
    for (int rg = 0; rg < 4; ++rg) {
      P[(size_t)(rbase + rg) * H_SZ + col] = (_Float16)acc[nt][rg];
    }
  }
}

// ---------------- k2: r7's proven MFMA recurrence, per-K-tile asm split ----
// Structure verbatim from the 229-us R0/R6 kernel. Only change: the per-step
// x value is gathered from P via idx (row id = s_load, block-uniform; P-load
// coalesced 512 B/wave, L2-resident) with the same 1-step prefetch rotation
// that covered the old x stream.
#define LDFRAG(C, KT, R0, R1, R2, R3) { \
  uint4 q = Wf4[(((size_t)(w * 4 + C) * 8 + KT) * 64) + lane]; \
  asm volatile("v_accvgpr_write_b32 a" #R0 ", %0" :: "v"(q.x) : "a" #R0); \
  asm volatile("v_accvgpr_write_b32 a" #R1 ", %0" :: "v"(q.y) : "a" #R1); \
  asm volatile("v_accvgpr_write_b32 a" #R2 ", %0" :: "v"(q.z) : "a" #R2); \
  asm volatile("v_accvgpr_write_b32 a" #R3 ", %0" :: "v"(q.w) : "a" #R3); }

// kt=0: fresh accumulators from pinned zero
#define MFMA_K0(A0, Z) \
  asm volatile( \
    "v_mfma_f32_16x16x32_f16 %[t0], %[a], a[0:3],   %[z]\n\t" \
    "v_mfma_f32_16x16x32_f16 %[t1], %[a], a[32:35], %[z]\n\t" \
    "v_mfma_f32_16x16x32_f16 %[t2], %[a], a[64:67], %[z]\n\t" \
    "v_mfma_f32_16x16x32_f16 %[t3], %[a], a[96:99], %[z]" \
    : [t0] "=&v"(acc0), [t1] "=&v"(acc1), [t2] "=&v"(acc2), [t3] "=&v"(acc3) \
    : [a] "v"(A0), [z] "v"(Z));

#define MFMA_KT(A0, B0, B1, B2, B3) \
  asm volatile( \
    "v_mfma_f32_16x16x32_f16 %[t0], %[a], a[" #B0 "], %[t0]\n\t" \
    "v_mfma_f32_16x16x32_f16 %[t1], %[a], a[" #B1 "], %[t1]\n\t" \
    "v_mfma_f32_16x16x32_f16 %[t2], %[a], a[" #B2 "], %[t2]\n\t" \
    "v_mfma_f32_16x16x32_f16 %[t3], %[a], a[" #B3 "], %[t3]" \
    : [t0] "+v"(acc0), [t1] "+v"(acc1), [t2] "+v"(acc2), [t3] "+v"(acc3) \
    : [a] "v"(A0));

#define MFMA_K7(A0, B0, B1, B2, B3) \
  asm volatile( \
    "v_mfma_f32_16x16x32_f16 %[t0], %[a], a[" #B0 "], %[t0]\n\t" \
    "v_mfma_f32_16x16x32_f16 %[t1], %[a], a[" #B1 "], %[t1]\n\t" \
    "v_mfma_f32_16x16x32_f16 %[t2], %[a], a[" #B2 "], %[t2]\n\t" \
    "v_mfma_f32_16x16x32_f16 %[t3], %[a], a[" #B3 "], %[t3]\n\t" \
    "s_nop 7\n\t" \
    "s_nop 7" \
    : [t0] "+v"(acc0), [t1] "+v"(acc1), [t2] "+v"(acc2), [t3] "+v"(acc3) \
    : [a] "v"(A0));

__global__ __launch_bounds__(256) void k2_rnn(
    const _Float16* __restrict__ Wf,
    const _Float16* __restrict__ P,
    const int* __restrict__ idx,
    const float* __restrict__ Bh,
    float* __restrict__ hout,
    float* __restrict__ hidout)
{
  const int b    = blockIdx.x;
  const int tid  = threadIdx.x;
  const int w    = tid >> 6;
  const int lane = tid & 63;
  const int quad = lane >> 4;
  __shared__ __align__(16) _Float16 hb[2][H_SZ];   // h as f16, double-buffered
  const uint4* Wf4 = (const uint4*)Wf;

  LDFRAG(0,0,  0,  1,  2,  3)  LDFRAG(0,1,  4,  5,  6,  7)
  LDFRAG(0,2,  8,  9, 10, 11)  LDFRAG(0,3, 12, 13, 14, 15)
  LDFRAG(0,4, 16, 17, 18, 19)  LDFRAG(0,5, 20, 21, 22, 23)
  LDFRAG(0,6, 24, 25, 26, 27)  LDFRAG(0,7, 28, 29, 30, 31)
  LDFRAG(1,0, 32, 33, 34, 35)  LDFRAG(1,1, 36, 37, 38, 39)
  LDFRAG(1,2, 40, 41, 42, 43)  LDFRAG(1,3, 44, 45, 46, 47)
  LDFRAG(1,4, 48, 49, 50, 51)  LDFRAG(1,5, 52, 53, 54, 55)
  LDFRAG(1,6, 56, 57, 58, 59)  LDFRAG(1,7, 60, 61, 62, 63)
  LDFRAG(2,0, 64, 65, 66, 67)  LDFRAG(2,1, 68, 69, 70, 71)
  LDFRAG(2,2, 72, 73, 74, 75)  LDFRAG(2,3, 76, 77, 78, 79)
  LDFRAG(2,4, 80, 81, 82, 83)  LDFRAG(2,5, 84, 85, 86, 87)
  LDFRAG(2,6, 88, 89, 90, 91)  LDFRAG(2,7, 92, 93, 94, 95)
  LDFRAG(3,0, 96, 97, 98, 99)  LDFRAG(3,1,100,101,102,103)
  LDFRAG(3,2,104,105,106,107)  LDFRAG(3,3,108,109,110,111)
  LDFRAG(3,4,112,113,114,115)  LDFRAG(3,5,116,117,118,119)
  LDFRAG(3,6,120,121,122,123)  LDFRAG(3,7,124,125,126,127)

  const float bhj = Bh[tid];
  const int* idxb = idx + b * T_SZ;
  int rowN = idxb[1];                          // row id for t=1
  _Float16 xq = P[(size_t)idxb[0] * H_SZ + tid];   // x value for t=0
  f32x4 zero4 = {0.f, 0.f, 0.f, 0.f};
  asm volatile("" : "+v"(zero4));        // pin: no remat-mov adjacent to MFMA srcC
  hb[1][tid] = (_Float16)0.f;            // t=0 reads buffer 1 = zeros
  float hval = 0.f;
  __syncthreads();

#pragma unroll 1
  for (int t = 0; t < T_SZ; ++t) {
    int t2 = t + 2; t2 = t2 > 511 ? 511 : t2;
    int rowN2 = idxb[t2];                           // s_load, 2 steps ahead
    _Float16 xn = P[(size_t)rowN * H_SZ + tid];     // x for t+1, 1 step cover
    const _Float16* hr = hb[(t + 1) & 1];
    // A fragments: h[kt*32+quad*8 .. +7], same for all 16 rows (quad-broadcast)
    half8 va0 = *(const half8*)(hr +   0 + quad * 8);
    half8 va1 = *(const half8*)(hr +  32 + quad * 8);
    half8 va2 = *(const half8*)(hr +  64 + quad * 8);
    half8 va3 = *(const half8*)(hr +  96 + quad * 8);
    half8 va4 = *(const half8*)(hr + 128 + quad * 8);
    half8 va5 = *(const half8*)(hr + 160 + quad * 8);
    half8 va6 = *(const half8*)(hr + 192 + quad * 8);
    half8 va7 = *(const half8*)(hr + 224 + quad * 8);
    f32x4 acc0, acc1, acc2, acc3;
    MFMA_K0(va0, zero4)
    MFMA_KT(va1,   4:7,  36:39,  68:71, 100:103)
    MFMA_KT(va2,  8:11,  40:43,  72:75, 104:107)
    MFMA_KT(va3, 12:15,  44:47,  76:79, 108:111)
    MFMA_KT(va4, 16:19,  48:51,  80:83, 112:115)
    MFMA_KT(va5, 20:23,  52:55,  84:87, 116:119)
    MFMA_KT(va6, 24:27,  56:59,  88:91, 120:123)
    MFMA_K7(va7, 28:31,  60:63,  92:95, 124:127)
    // D rows identical (A rows replicated); lane (quad q, n16) takes tile q:
    float v0 = acc0[0], v1 = acc1[0], v2 = acc2[0], v3 = acc3[0];
    float ylo = (quad & 1) ? v1 : v0;
    float yhi = (quad & 1) ? v3 : v2;
    float y   = (quad & 2) ? yhi : ylo;     // y = (h @ Whh)[tid]
    hval = fast_tanh(y + (float)xq + bhj);
    hb[t & 1][tid] = (_Float16)hval;
    __syncthreads();
    xq = xn; rowN = rowN2;
  }
  hout[b * H_SZ + tid] = hval;
  hidout[b * H_SZ + tid] = hval;
}

// ---------------- k3: out = hidden @ Wy + By  (all f32) ----------------
__global__ __launch_bounds__(256) void k3_out(
    const float* __restrict__ h,
    const float* __restrict__ Wy,
    const float* __restrict__ By,
    float* __restrict__ out)
{
  __shared__ float hs[H_SZ];
  const int c = blockIdx.x;   // vocab chunk
  const int b = blockIdx.y;   // batch
  const int v = c * 256 + threadIdx.x;
  hs[threadIdx.x] = h[b * H_SZ + threadIdx.x];
  __syncthreads();
  float acc = By[v];
#pragma unroll 8
  for (int jj = 0; jj < H_SZ; ++jj) {
    acc += hs[jj] * Wy[(size_t)jj * V_SZ + v];
  }
  out[(size_t)b * V_SZ + v] = acc;
}

extern "C" void kernel_launch(void* const* d_in, const int* in_sizes, int n_in,
                              void* d_out, int out_size, void* d_ws, size_t ws_size,
                              hipStream_t stream)
{
  const int*   idx = (const int*)d_in[0];
  const float* emb = (const float*)d_in[1];
  const float* Wxh = (const float*)d_in[2];
  const float* Whh = (const float*)d_in[3];
  const float* Wy  = (const float*)d_in[4];
  const float* By  = (const float*)d_in[5];
  const float* Bh  = (const float*)d_in[6];

  char* ws = (char*)d_ws;
  _Float16* P    = (_Float16*)(ws + WS_P);
  _Float16* Wtf  = (_Float16*)(ws + WS_WT);
  _Float16* Wf   = (_Float16*)(ws + WS_WF);
  float*    hbuf = (float*)(ws + WS_H);

  float* out    = (float*)d_out;
  float* hidout = out + (size_t)B_SZ * V_SZ;

  k0_convert<<<768, 256, 0, stream>>>(Wxh, Whh, Wtf, Wf);
  k1_xproj  <<<48, 256, 0, stream>>>(emb, Wtf, P);
  k2_rnn    <<<64, 256, 0, stream>>>(Wf, P, idx, Bh, hbuf, hidout);
  k3_out    <<<dim3(12, 64), 256, 0, stream>>>(hbuf, Wy, By, out);
}

// Round 8
// 360.495 us; speedup vs baseline: 1.6976x; 1.0262x over previous
//
#include <hip/hip_runtime.h>
#include <hip/hip_bf16.h>

typedef _Float16 half8 __attribute__((ext_vector_type(8)));
typedef float f32x4 __attribute__((ext_vector_type(4)));

#define B_SZ 64
#define T_SZ 512
#define E_SZ 768
#define H_SZ 256
#define V_SZ 3072

// workspace layout (bytes)
#define WS_P     0u          // _Float16 P[3072][256] = emb @ Wxh   1,572,864 B
#define WS_WT    16777216u   // _Float16 Wtf[24][1024][8] (Wxh panels, frag order) 393,216 B
#define WS_WF    17170432u   // _Float16 Wf[65536] Whh MFMA-B    131,072 B
#define WS_H     17301504u   // float    h[64][256]               65,536 B

// fast tanh: 1 - 2/(1+exp(2x)); exact at +/-inf, ~1e-6 rel err
static __device__ __forceinline__ float fast_tanh(float x) {
  float e = __builtin_amdgcn_exp2f(x * 2.8853900817779268f); // exp(2x)
  return 1.0f - 2.0f * __builtin_amdgcn_rcpf(1.0f + e);
}

// ---------------- k0: prep f16 weight layouts (small) ----------------
// R7->R8: flipped to COALESCED READS + scattered 2B writes (was strided 4B
// reads at 1-3 KB + contiguous writes). Same bijections, inverted:
// Wtf: src (e,n) -> ki=e>>5, kb=(e>>3)&3, j=e&7, f=((n>>4)<<6)|(kb<<4)|(n&15),
//      flat = ki*8192 + f*8 + j   (inverse of R7's forward map, both checked)
// Wf:  src (row,col) -> kt=row>>5, quad=(row>>3)&3, j=row&7, nt=col>>4,
//      lane=(quad<<4)|(col&15), flat = ((nt*8+kt)*64+lane)*8 + j
__global__ __launch_bounds__(256) void k0_convert(
    const float* __restrict__ Wxh,
    const float* __restrict__ Whh,
    _Float16* __restrict__ Wtf,
    _Float16* __restrict__ Wf)
{
  int gid = blockIdx.x * 256 + threadIdx.x;           // 768 WGs = 196608
  if (gid < E_SZ * H_SZ) {                            // gid = e*256 + n (coalesced)
    int e = gid >> 8, n = gid & 255;
    float v = Wxh[gid];
    int ki = e >> 5, kb = (e >> 3) & 3, j = e & 7;
    int f  = ((n >> 4) << 6) | (kb << 4) | (n & 15);
    Wtf[(size_t)ki * 8192 + (size_t)f * 8 + j] = (_Float16)v;
  }
  if (gid < 65536) {                                  // gid = row*256 + col (coalesced)
    int row = gid >> 8, col = gid & 255;
    float v = Whh[gid];
    int kt = row >> 5, quad = (row >> 3) & 3, j = row & 7;
    int nt = col >> 4;
    int lane = (quad << 4) | (col & 15);
    Wf[(((size_t)(nt * 8 + kt) * 64 + lane) * 8) + j] = (_Float16)v;
  }
}

// ---------------- k1: P[v,:] = emb[v,:] @ Wxh  (MFMA f16, vocab table) ---------
// Projects the 3072-row table once (10.7x less work than per-(t,b)); k2
// gathers from P. Inner loop = proven R6 k1. Grid: 48 blocks x 64 rows.
__global__ __launch_bounds__(256) void k1_xproj(
    const float* __restrict__ emb,
    const _Float16* __restrict__ Wtf,
    _Float16* __restrict__ P)
{
  const int tid  = threadIdx.x;
  const int w    = tid >> 6;
  const int lane = tid & 63;
  const int m16  = lane & 15;
  const int quad = lane >> 4;
  const int r = blockIdx.x * 64 + w * 16 + m16;     // vocab row, 0..3071
  const float* Arow = emb + (size_t)r * E_SZ + quad * 8;   // A[m][k=quad*8+j]

  __shared__ __align__(16) _Float16 bp[2][16 * 64 * 8]; // 2 x 16KB fragment panels
  uint4 stg[4];
#pragma unroll
  for (int pp = 0; pp < 4; ++pp)
    stg[pp] = *(const uint4*)(Wtf + (size_t)(tid + 256 * pp) * 8);  // ki = 0
  f32x4 af0 = *(const f32x4*)(Arow);
  f32x4 af1 = *(const f32x4*)(Arow + 4);

  f32x4 acc[16];
#pragma unroll
  for (int n = 0; n < 16; ++n) { f32x4 z = {0.f, 0.f, 0.f, 0.f}; acc[n] = z; }

  // stage panel 0
#pragma unroll
  for (int pp = 0; pp < 4; ++pp)
    *(uint4*)(bp[0] + (size_t)(tid + 256 * pp) * 8) = stg[pp];
  __syncthreads();

#pragma unroll 1
  for (int ki = 0; ki < 24; ++ki) {
    const _Float16* cur = bp[ki & 1];
    f32x4 af0n = af0, af1n = af1;
    if (ki < 23) {                            // prefetch next panel + next A
#pragma unroll
      for (int pp = 0; pp < 4; ++pp)
        stg[pp] = *(const uint4*)(Wtf + (size_t)(ki + 1) * 8192
                                      + (size_t)(tid + 256 * pp) * 8);
      af0n = *(const f32x4*)(Arow + (ki + 1) * 32);
      af1n = *(const f32x4*)(Arow + (ki + 1) * 32 + 4);
    }
    half8 a;
#pragma unroll
    for (int e = 0; e < 4; ++e) { a[e] = (_Float16)af0[e]; a[4 + e] = (_Float16)af1[e]; }
#pragma unroll
    for (int nt = 0; nt < 16; ++nt) {
      half8 bb = *(const half8*)(cur + (size_t)(nt * 64 + lane) * 8);
      acc[nt] = __builtin_amdgcn_mfma_f32_16x16x32_f16(a, bb, acc[nt], 0, 0, 0);
    }
    if (ki < 23) {                            // write next buffer, one barrier
#pragma unroll
      for (int pp = 0; pp < 4; ++pp)
        *(uint4*)(bp[(ki + 1) & 1] + (size_t)(tid + 256 * pp) * 8) = stg[pp];
      __syncthreads();
    }
    af0 = af0n; af1 = af1n;
  }
  const int rbase = blockIdx.x * 64 + w * 16 + quad * 4;  // C/D: col=lane&15, row=quad*4+reg
#pragma unroll
  for (int nt = 0; nt < 16; ++nt) {
    const int col = nt * 16 + m16;
#pragma unroll
    for (int rg = 0; rg < 4; ++rg) {
      P[(size_t)(rbase + rg) * H_SZ + col] = (_Float16)acc[nt][rg];
    }
  }
}

// ---------------- k2: r7's proven MFMA recurrence, per-K-tile asm split ----
// R7 regression fix: the P-gather's load had <1-step cover (address depends
// on rowN -> compiler issues it late; the xq=xn rotation then waits on a
// young load). R8 uses the R1-proven reload-in-place pattern: 2 x registers
// (time loop unrolled x2); each is CONSUMED first ((float)xA forces the wait
// on a load issued a full iteration = ~2 steps ago) then reloaded for t+2.
// Row ids rotate one iteration ahead (s_load, 2-step cover). MFMA body,
// LDS layout, epilogue verbatim from the 229-us kernel.
#define LDFRAG(C, KT, R0, R1, R2, R3) { \
  uint4 q = Wf4[(((size_t)(w * 4 + C) * 8 + KT) * 64) + lane]; \
  asm volatile("v_accvgpr_write_b32 a" #R0 ", %0" :: "v"(q.x) : "a" #R0); \
  asm volatile("v_accvgpr_write_b32 a" #R1 ", %0" :: "v"(q.y) : "a" #R1); \
  asm volatile("v_accvgpr_write_b32 a" #R2 ", %0" :: "v"(q.z) : "a" #R2); \
  asm volatile("v_accvgpr_write_b32 a" #R3 ", %0" :: "v"(q.w) : "a" #R3); }

// kt=0: fresh accumulators from pinned zero
#define MFMA_K0(A0, Z) \
  asm volatile( \
    "v_mfma_f32_16x16x32_f16 %[t0], %[a], a[0:3],   %[z]\n\t" \
    "v_mfma_f32_16x16x32_f16 %[t1], %[a], a[32:35], %[z]\n\t" \
    "v_mfma_f32_16x16x32_f16 %[t2], %[a], a[64:67], %[z]\n\t" \
    "v_mfma_f32_16x16x32_f16 %[t3], %[a], a[96:99], %[z]" \
    : [t0] "=&v"(acc0), [t1] "=&v"(acc1), [t2] "=&v"(acc2), [t3] "=&v"(acc3) \
    : [a] "v"(A0), [z] "v"(Z));

#define MFMA_KT(A0, B0, B1, B2, B3) \
  asm volatile( \
    "v_mfma_f32_16x16x32_f16 %[t0], %[a], a[" #B0 "], %[t0]\n\t" \
    "v_mfma_f32_16x16x32_f16 %[t1], %[a], a[" #B1 "], %[t1]\n\t" \
    "v_mfma_f32_16x16x32_f16 %[t2], %[a], a[" #B2 "], %[t2]\n\t" \
    "v_mfma_f32_16x16x32_f16 %[t3], %[a], a[" #B3 "], %[t3]" \
    : [t0] "+v"(acc0), [t1] "+v"(acc1), [t2] "+v"(acc2), [t3] "+v"(acc3) \
    : [a] "v"(A0));

#define MFMA_K7(A0, B0, B1, B2, B3) \
  asm volatile( \
    "v_mfma_f32_16x16x32_f16 %[t0], %[a], a[" #B0 "], %[t0]\n\t" \
    "v_mfma_f32_16x16x32_f16 %[t1], %[a], a[" #B1 "], %[t1]\n\t" \
    "v_mfma_f32_16x16x32_f16 %[t2], %[a], a[" #B2 "], %[t2]\n\t" \
    "v_mfma_f32_16x16x32_f16 %[t3], %[a], a[" #B3 "], %[t3]\n\t" \
    "s_nop 7\n\t" \
    "s_nop 7" \
    : [t0] "+v"(acc0), [t1] "+v"(acc1), [t2] "+v"(acc2), [t3] "+v"(acc3) \
    : [a] "v"(A0));

__global__ __launch_bounds__(256) void k2_rnn(
    const _Float16* __restrict__ Wf,
    const _Float16* __restrict__ P,
    const int* __restrict__ idx,
    const float* __restrict__ Bh,
    float* __restrict__ hout,
    float* __restrict__ hidout)
{
  const int b    = blockIdx.x;
  const int tid  = threadIdx.x;
  const int w    = tid >> 6;
  const int lane = tid & 63;
  const int quad = lane >> 4;
  __shared__ __align__(16) _Float16 hb[2][H_SZ];   // h as f16, double-buffered
  const uint4* Wf4 = (const uint4*)Wf;

  LDFRAG(0,0,  0,  1,  2,  3)  LDFRAG(0,1,  4,  5,  6,  7)
  LDFRAG(0,2,  8,  9, 10, 11)  LDFRAG(0,3, 12, 13, 14, 15)
  LDFRAG(0,4, 16, 17, 18, 19)  LDFRAG(0,5, 20, 21, 22, 23)
  LDFRAG(0,6, 24, 25, 26, 27)  LDFRAG(0,7, 28, 29, 30, 31)
  LDFRAG(1,0, 32, 33, 34, 35)  LDFRAG(1,1, 36, 37, 38, 39)
  LDFRAG(1,2, 40, 41, 42, 43)  LDFRAG(1,3, 44, 45, 46, 47)
  LDFRAG(1,4, 48, 49, 50, 51)  LDFRAG(1,5, 52, 53, 54, 55)
  LDFRAG(1,6, 56, 57, 58, 59)  LDFRAG(1,7, 60, 61, 62, 63)
  LDFRAG(2,0, 64, 65, 66, 67)  LDFRAG(2,1, 68, 69, 70, 71)
  LDFRAG(2,2, 72, 73, 74, 75)  LDFRAG(2,3, 76, 77, 78, 79)
  LDFRAG(2,4, 80, 81, 82, 83)  LDFRAG(2,5, 84, 85, 86, 87)
  LDFRAG(2,6, 88, 89, 90, 91)  LDFRAG(2,7, 92, 93, 94, 95)
  LDFRAG(3,0, 96, 97, 98, 99)  LDFRAG(3,1,100,101,102,103)
  LDFRAG(3,2,104,105,106,107)  LDFRAG(3,3,108,109,110,111)
  LDFRAG(3,4,112,113,114,115)  LDFRAG(3,5,116,117,118,119)
  LDFRAG(3,6,120,121,122,123)  LDFRAG(3,7,124,125,126,127)

  const float bhj = Bh[tid];
  const int* idxb = idx + b * T_SZ;
  int rowA = idxb[2];                               // row for t=2 (next xA refill)
  int rowB = idxb[3];                               // row for t=3 (next xB refill)
  _Float16 xA = P[(size_t)idxb[0] * H_SZ + tid];    // x for t=0
  _Float16 xB = P[(size_t)idxb[1] * H_SZ + tid];    // x for t=1
  f32x4 zero4 = {0.f, 0.f, 0.f, 0.f};
  asm volatile("" : "+v"(zero4));        // pin: no remat-mov adjacent to MFMA srcC
  hb[1][tid] = (_Float16)0.f;            // t=0 reads buffer 1 = zeros
  float hval = 0.f;
  __syncthreads();

#define K2_STEP(HR, HW, XV)                                              \
  {                                                                      \
    const _Float16* hr = (HR);                                           \
    half8 va0 = *(const half8*)(hr +   0 + quad * 8);                    \
    half8 va1 = *(const half8*)(hr +  32 + quad * 8);                    \
    half8 va2 = *(const half8*)(hr +  64 + quad * 8);                    \
    half8 va3 = *(const half8*)(hr +  96 + quad * 8);                    \
    half8 va4 = *(const half8*)(hr + 128 + quad * 8);                    \
    half8 va5 = *(const half8*)(hr + 160 + quad * 8);                    \
    half8 va6 = *(const half8*)(hr + 192 + quad * 8);                    \
    half8 va7 = *(const half8*)(hr + 224 + quad * 8);                    \
    f32x4 acc0, acc1, acc2, acc3;                                        \
    MFMA_K0(va0, zero4)                                                  \
    MFMA_KT(va1,   4:7,  36:39,  68:71, 100:103)                         \
    MFMA_KT(va2,  8:11,  40:43,  72:75, 104:107)                         \
    MFMA_KT(va3, 12:15,  44:47,  76:79, 108:111)                         \
    MFMA_KT(va4, 16:19,  48:51,  80:83, 112:115)                         \
    MFMA_KT(va5, 20:23,  52:55,  84:87, 116:119)                         \
    MFMA_KT(va6, 24:27,  56:59,  88:91, 120:123)                         \
    MFMA_K7(va7, 28:31,  60:63,  92:95, 124:127)                         \
    float v0 = acc0[0], v1 = acc1[0], v2 = acc2[0], v3 = acc3[0];        \
    float ylo = (quad & 1) ? v1 : v0;                                    \
    float yhi = (quad & 1) ? v3 : v2;                                    \
    float y   = (quad & 2) ? yhi : ylo;     /* y = (h @ Whh)[tid] */     \
    hval = fast_tanh(y + (XV) + bhj);                                    \
    (HW)[tid] = (_Float16)hval;                                          \
    __syncthreads();                                                     \
  }

#pragma unroll 1
  for (int tt = 0; tt < 256; ++tt) {
    // ---- step A: t = 2tt, read hb[1], write hb[0]
    float xvA = (float)xA;                 // wait: xA load issued 1 iter (~2 steps) ago
    xA = P[(size_t)rowA * H_SZ + tid];     // refill for t = 2tt+2 (same register)
    int t4 = 2 * tt + 4; t4 = t4 > 511 ? 511 : t4;
    rowA = idxb[t4];                       // s_load, consumed next iteration
    K2_STEP(hb[1], hb[0], xvA)
    // ---- step B: t = 2tt+1, read hb[0], write hb[1]
    float xvB = (float)xB;
    xB = P[(size_t)rowB * H_SZ + tid];     // refill for t = 2tt+3
    int t5 = 2 * tt + 5; t5 = t5 > 511 ? 511 : t5;
    rowB = idxb[t5];
    K2_STEP(hb[0], hb[1], xvB)
  }
#undef K2_STEP
  hout[b * H_SZ + tid] = hval;
  hidout[b * H_SZ + tid] = hval;
}

// ---------------- k3: out = hidden @ Wy + By  (all f32) ----------------
// R8: 4 independent accumulators break the 256-deep dependent FMA chain.
__global__ __launch_bounds__(256) void k3_out(
    const float* __restrict__ h,
    const float* __restrict__ Wy,
    const float* __restrict__ By,
    float* __restrict__ out)
{
  __shared__ float hs[H_SZ];
  const int c = blockIdx.x;   // vocab chunk
  const int b = blockIdx.y;   // batch
  const int v = c * 256 + threadIdx.x;
  hs[threadIdx.x] = h[b * H_SZ + threadIdx.x];
  __syncthreads();
  float a0 = By[v], a1 = 0.f, a2 = 0.f, a3 = 0.f;
#pragma unroll 4
  for (int jj = 0; jj < H_SZ; jj += 4) {
    a0 += hs[jj + 0] * Wy[(size_t)(jj + 0) * V_SZ + v];
    a1 += hs[jj + 1] * Wy[(size_t)(jj + 1) * V_SZ + v];
    a2 += hs[jj + 2] * Wy[(size_t)(jj + 2) * V_SZ + v];
    a3 += hs[jj + 3] * Wy[(size_t)(jj + 3) * V_SZ + v];
  }
  out[(size_t)b * V_SZ + v] = (a0 + a1) + (a2 + a3);
}

extern "C" void kernel_launch(void* const* d_in, const int* in_sizes, int n_in,
                              void* d_out, int out_size, void* d_ws, size_t ws_size,
                              hipStream_t stream)
{
  const int*   idx = (const int*)d_in[0];
  const float* emb = (const float*)d_in[1];
  const float* Wxh = (const float*)d_in[2];
  const float* Whh = (const float*)d_in[3];
  const float* Wy  = (const float*)d_in[4];
  const float* By  = (const float*)d_in[5];
  const float* Bh  = (const float*)d_in[6];

  char* ws = (char*)d_ws;
  _Float16* P    = (_Float16*)(ws + WS_P);
  _Float16* Wtf  = (_Float16*)(ws + WS_WT);
  _Float16* Wf   = (_Float16*)(ws + WS_WF);
  float*    hbuf = (float*)(ws + WS_H);

  float* out    = (float*)d_out;
  float* hidout = out + (size_t)B_SZ * V_SZ;

  k0_convert<<<768, 256, 0, stream>>>(Wxh, Whh, Wtf, Wf);
  k1_xproj  <<<48, 256, 0, stream>>>(emb, Wtf, P);
  k2_rnn    <<<64, 256, 0, stream>>>(Wf, P, idx, Bh, hbuf, hidout);
  k3_out    <<<dim3(12, 64), 256, 0, stream>>>(hbuf, Wy, By, out);
}